// Round 3
// baseline (7082.822 us; speedup 1.0000x reference)
//
#include <hip/hip_runtime.h>
#include <math.h>
#include <stdint.h>

#define N_NODES 50000
#define N_EDGES 400000
#define N_T 4
#define N_R 8
#define N_H 8
#define DKD 32
#define D 256
#define TM 64
#define PROJ_BLOCKS ((N_NODES + TM - 1) / TM + N_T)   // 786 >= sum of per-type ceils

typedef __bf16 v8bf __attribute__((ext_vector_type(8)));
typedef float v4f __attribute__((ext_vector_type(4)));
typedef unsigned short u16;

__device__ __forceinline__ float bf2f(u16 u) {
    return __uint_as_float(((unsigned int)u) << 16);
}
__device__ __forceinline__ u16 f2bf(float f) {
    unsigned int u = __float_as_uint(f);
    u += 0x7fffu + ((u >> 16) & 1u);          // RNE
    return (u16)(u >> 16);
}

// load 32 contiguous bf16 -> 32 floats (4x 16B loads)
__device__ __forceinline__ void load_bf32(const u16* __restrict__ p, float* f) {
    const uint4* p4 = (const uint4*)p;
    #pragma unroll
    for (int j = 0; j < 4; j++) {
        uint4 u = p4[j];
        f[8 * j + 0] = __uint_as_float(u.x << 16);
        f[8 * j + 1] = __uint_as_float(u.x & 0xffff0000u);
        f[8 * j + 2] = __uint_as_float(u.y << 16);
        f[8 * j + 3] = __uint_as_float(u.y & 0xffff0000u);
        f[8 * j + 4] = __uint_as_float(u.z << 16);
        f[8 * j + 5] = __uint_as_float(u.z & 0xffff0000u);
        f[8 * j + 6] = __uint_as_float(u.w << 16);
        f[8 * j + 7] = __uint_as_float(u.w & 0xffff0000u);
    }
}

// ---------------- f32 -> bf16 conversion (weights) ----------------
__global__ __launch_bounds__(256) void k_cvt4(const float4* __restrict__ s,
                                              ushort4* __restrict__ d, int n4) {
    int i = blockIdx.x * 256 + threadIdx.x;
    if (i < n4) {
        float4 v = s[i];
        ushort4 o;
        o.x = f2bf(v.x); o.y = f2bf(v.y); o.z = f2bf(v.z); o.w = f2bf(v.w);
        d[i] = o;
    }
}

// ---------------- bucketing by node type ----------------
__global__ void k_hist(const int* __restrict__ nt, int* __restrict__ cnt) {
    int n = blockIdx.x * blockDim.x + threadIdx.x;
    if (n < N_NODES) atomicAdd(&cnt[nt[n]], 1);
}

__global__ void k_scan(const int* __restrict__ cnt, int* __restrict__ off,
                       int* __restrict__ toff) {
    int o = 0, to = 0;
    for (int t = 0; t < N_T; t++) {
        off[t] = o; toff[t] = to;
        o += cnt[t]; to += (cnt[t] + TM - 1) / TM;
    }
    off[N_T] = o; toff[N_T] = to;
}

__global__ void k_scatter(const int* __restrict__ nt, const int* __restrict__ off,
                          int* __restrict__ cur, int* __restrict__ order) {
    int n = blockIdx.x * blockDim.x + threadIdx.x;
    if (n >= N_NODES) return;
    int t = nt[n];
    int pos = off[t] + atomicAdd(&cur[t], 1);
    order[pos] = n;
}

// ---------------- fused typed K/Q/V projection (MFMA) ----------------
// x: f32, staged to LDS as bf16; W: pre-converted bf16; outputs bf16
__global__ __launch_bounds__(256) void k_proj(
    const float* __restrict__ x, const int* __restrict__ order,
    const int* __restrict__ off, const int* __restrict__ toff,
    const u16* __restrict__ Wkb, const float* __restrict__ bk,
    const u16* __restrict__ Wqb, const float* __restrict__ bq,
    const u16* __restrict__ Wvb, const float* __restrict__ bv,
    u16* __restrict__ Kb, u16* __restrict__ Qb, u16* __restrict__ Vb) {
    __shared__ __align__(16) u16 xs[TM][D + 8];   // +8 pad breaks bank aliasing
    int b = blockIdx.x;
    int t = -1;
    #pragma unroll
    for (int i = 0; i < N_T; i++)
        if (b >= toff[i] && b < toff[i + 1]) t = i;
    if (t < 0) return;
    int nodeBase = off[t] + (b - toff[t]) * TM;
    int count = min(TM, off[t + 1] - nodeBase);
    int tid = threadIdx.x;

    for (int j = tid; j < TM * (D / 4); j += 256) {  // 64 rows x 64 float4 chunks
        int row = j >> 6, ch = j & 63;
        float4 v = {0.f, 0.f, 0.f, 0.f};
        if (row < count) {
            int g = order[nodeBase + row];
            v = *(const float4*)(x + (size_t)g * D + ch * 4);
        }
        ushort4 o;
        o.x = f2bf(v.x); o.y = f2bf(v.y); o.z = f2bf(v.z); o.w = f2bf(v.w);
        *(ushort4*)&xs[row][ch * 4] = o;
    }
    __syncthreads();

    int lane = tid & 63, wave = tid >> 6;
    int m = lane & 15, quad = lane >> 4;
    v8bf a[8];
    #pragma unroll
    for (int ks = 0; ks < 8; ks++)
        a[ks] = *(const v8bf*)&xs[wave * 16 + m][ks * 32 + quad * 8];

    int grow[4]; bool vrow[4];
    #pragma unroll
    for (int r = 0; r < 4; r++) {
        int rowi = wave * 16 + quad * 4 + r;
        vrow[r] = (rowi < count);
        grow[r] = vrow[r] ? order[nodeBase + rowi] : 0;
    }

    const u16* Ws[3] = {Wkb + (size_t)t * D * D, Wqb + (size_t)t * D * D, Wvb + (size_t)t * D * D};
    const float* Bs[3] = {bk + t * D, bq + t * D, bv + t * D};
    u16* Os[3] = {Kb, Qb, Vb};

    for (int p = 0; p < 3; p++) {
        const u16* W = Ws[p];
        for (int dt = 0; dt < 16; dt++) {
            int dcol = dt * 16 + m;                  // C col = lane&15
            v4f acc = {0.f, 0.f, 0.f, 0.f};
            #pragma unroll
            for (int ks = 0; ks < 8; ks++) {
                v8bf bf = *(const v8bf*)(W + (size_t)dcol * D + ks * 32 + quad * 8);
                acc = __builtin_amdgcn_mfma_f32_16x16x32_bf16(a[ks], bf, acc, 0, 0, 0);
            }
            float bias = Bs[p][dcol];
            #pragma unroll
            for (int r = 0; r < 4; r++) {            // C row = quad*4 + r
                if (vrow[r])
                    Os[p][(size_t)grow[r] * D + dcol] = f2bf(acc[r] + bias);
            }
        }
    }
}

// ---------------- edge attention: ex + denom ----------------
__global__ __launch_bounds__(256) void k_edge_att(
    const u16* __restrict__ Kb, const u16* __restrict__ Qb,
    const int* __restrict__ src, const int* __restrict__ dst, const int* __restrict__ et,
    const u16* __restrict__ Ab, const float* __restrict__ pri,
    float* __restrict__ EX, float* __restrict__ DEN) {
    int idx = blockIdx.x * 256 + threadIdx.x;
    if (idx >= N_EDGES * N_H) return;
    int e = idx >> 3, h = idx & 7;
    int s = src[e], d = dst[e], r = et[e];

    float qv[DKD], kv[DKD];
    load_bf32(Qb + (size_t)d * D + h * DKD, qv);
    load_bf32(Kb + (size_t)s * D + h * DKD, kv);

    const u16* A = Ab + ((size_t)(r * N_H + h)) * DKD * DKD;
    float att = 0.f;
    #pragma unroll 4
    for (int d0 = 0; d0 < DKD; d0++) {
        const unsigned int* Ar = (const unsigned int*)(A + (size_t)d0 * DKD);
        float tmp = 0.f;
        #pragma unroll
        for (int j = 0; j < 16; j++) {
            unsigned int u = Ar[j];
            tmp += __uint_as_float(u << 16) * qv[2 * j]
                 + __uint_as_float(u & 0xffff0000u) * qv[2 * j + 1];
        }
        att += kv[d0] * tmp;
    }
    att *= pri[r * N_H + h] * 0.17677669529663687f;   // 1/sqrt(32)
    float ex = __expf(att);    // |att| ~ N(0,1): safe without max-subtraction
    EX[idx] = ex;
    unsafeAtomicAdd(&DEN[((size_t)d * N_R + r) * N_H + h], ex);
}

// ---------------- edge message: acc += w * (M_r v) ----------------
__global__ __launch_bounds__(256) void k_edge_msg(
    const u16* __restrict__ Vb,
    const int* __restrict__ src, const int* __restrict__ dst, const int* __restrict__ et,
    const u16* __restrict__ Mb, const float* __restrict__ EX,
    const float* __restrict__ DEN, float* __restrict__ ACC) {
    int idx = blockIdx.x * 256 + threadIdx.x;
    if (idx >= N_EDGES * N_H) return;
    int e = idx >> 3, h = idx & 7;
    int s = src[e], d = dst[e], r = et[e];

    float w = EX[idx] / DEN[((size_t)d * N_R + r) * N_H + h];

    float vv[DKD];
    load_bf32(Vb + (size_t)s * D + h * DKD, vv);

    const u16* M = Mb + ((size_t)(r * N_H + h)) * DKD * DKD;
    float msg[DKD];
    #pragma unroll
    for (int f = 0; f < DKD; f++) msg[f] = 0.f;
    #pragma unroll 4
    for (int d0 = 0; d0 < DKD; d0++) {
        float vd = vv[d0];
        const unsigned int* Mr = (const unsigned int*)(M + (size_t)d0 * DKD);
        #pragma unroll
        for (int j = 0; j < 16; j++) {
            unsigned int u = Mr[j];
            msg[2 * j]     += vd * __uint_as_float(u << 16);
            msg[2 * j + 1] += vd * __uint_as_float(u & 0xffff0000u);
        }
    }
    float* accp = ACC + (size_t)d * D + h * DKD;
    #pragma unroll
    for (int f = 0; f < DKD; f++)
        unsafeAtomicAdd(&accp[f], w * msg[f]);
}

// ---------------- t = acc / present-count, round to bf16 ----------------
__global__ __launch_bounds__(256) void k_node_t(
    const float* __restrict__ ACC, const float* __restrict__ DEN,
    u16* __restrict__ TBF) {
    int n = blockIdx.x;
    __shared__ float invp;
    if (threadIdx.x == 0) {
        int P = 0;
        #pragma unroll
        for (int r = 0; r < N_R; r++)
            P += (DEN[((size_t)n * N_R + r) * N_H] > 0.f) ? 1 : 0;
        invp = 1.f / (float)(P > 0 ? P : 1);
    }
    __syncthreads();
    int dd = threadIdx.x;
    TBF[(size_t)n * D + dd] = f2bf(ACC[(size_t)n * D + dd] * invp);
}

// ---------------- typed output linear + sigmoid-skip blend (MFMA) ----------------
__global__ __launch_bounds__(256) void k_out(
    const u16* __restrict__ TBF, const float* __restrict__ x,
    const int* __restrict__ order, const int* __restrict__ off, const int* __restrict__ toff,
    const u16* __restrict__ Wab, const float* __restrict__ ba,
    const float* __restrict__ skip, float* __restrict__ out) {
    __shared__ __align__(16) u16 xs[TM][D + 8];
    int b = blockIdx.x;
    int t = -1;
    #pragma unroll
    for (int i = 0; i < N_T; i++)
        if (b >= toff[i] && b < toff[i + 1]) t = i;
    if (t < 0) return;
    int nodeBase = off[t] + (b - toff[t]) * TM;
    int count = min(TM, off[t + 1] - nodeBase);
    int tid = threadIdx.x;

    for (int j = tid; j < TM * 32; j += 256) {       // TBF already bf16: 16B chunks
        int row = j >> 5, ch = j & 31;
        ushort4 z = {0, 0, 0, 0};
        if (row < count) {
            int g = order[nodeBase + row];
            const ushort4* p = (const ushort4*)(TBF + (size_t)g * D + ch * 8);
            *(ushort4*)&xs[row][ch * 8] = p[0];
            *(ushort4*)&xs[row][ch * 8 + 4] = p[1];
        } else {
            *(ushort4*)&xs[row][ch * 8] = z;
            *(ushort4*)&xs[row][ch * 8 + 4] = z;
        }
    }
    __syncthreads();

    int lane = tid & 63, wave = tid >> 6;
    int m = lane & 15, quad = lane >> 4;
    v8bf a[8];
    #pragma unroll
    for (int ks = 0; ks < 8; ks++)
        a[ks] = *(const v8bf*)&xs[wave * 16 + m][ks * 32 + quad * 8];

    int grow[4]; bool vrow[4];
    #pragma unroll
    for (int r = 0; r < 4; r++) {
        int rowi = wave * 16 + quad * 4 + r;
        vrow[r] = (rowi < count);
        grow[r] = vrow[r] ? order[nodeBase + rowi] : 0;
    }

    float sv = skip[t];
    float alpha = 1.f / (1.f + __expf(-sv));
    float beta = 1.f - alpha;
    const u16* W = Wab + (size_t)t * D * D;

    for (int dt = 0; dt < 16; dt++) {
        int dcol = dt * 16 + m;
        v4f acc = {0.f, 0.f, 0.f, 0.f};
        #pragma unroll
        for (int ks = 0; ks < 8; ks++) {
            v8bf bf = *(const v8bf*)(W + (size_t)dcol * D + ks * 32 + quad * 8);
            acc = __builtin_amdgcn_mfma_f32_16x16x32_bf16(a[ks], bf, acc, 0, 0, 0);
        }
        float bias = ba[t * D + dcol];
        #pragma unroll
        for (int r = 0; r < 4; r++) {
            if (vrow[r]) {
                size_t o = (size_t)grow[r] * D + dcol;
                out[o] = alpha * (acc[r] + bias) + beta * x[o];
            }
        }
    }
}

// ---------------- launch ----------------
extern "C" void kernel_launch(void* const* d_in, const int* in_sizes, int n_in,
                              void* d_out, int out_size, void* d_ws, size_t ws_size,
                              hipStream_t stream) {
    const float* x       = (const float*)d_in[0];
    const int* node_type = (const int*)d_in[1];
    const int* src       = (const int*)d_in[2];
    const int* dst       = (const int*)d_in[3];
    const int* etype     = (const int*)d_in[4];
    const float* Wk = (const float*)d_in[5];
    const float* bk = (const float*)d_in[6];
    const float* Wq = (const float*)d_in[7];
    const float* bq = (const float*)d_in[8];
    const float* Wv = (const float*)d_in[9];
    const float* bv = (const float*)d_in[10];
    const float* Wa = (const float*)d_in[11];
    const float* ba = (const float*)d_in[12];
    const float* rel_pri = (const float*)d_in[13];
    const float* rel_att = (const float*)d_in[14];
    const float* rel_msg = (const float*)d_in[15];
    const float* skip    = (const float*)d_in[16];
    float* out = (float*)d_out;
    char* ws = (char*)d_ws;

    // ws layout (~79.4 MB total):
    //   [0,SZH) Kb | [SZH,2SZH) Qb | [2SZH,3SZH) Vb      (bf16 node tensors)
    //   ACC (f32 51.2MB) aliases Kb+Qb (zeroed after att pass)
    //   TBF (bf16)       aliases Vb   (written after msg pass)
    //   [3SZH, ...) Wkb/Wqb/Wvb/Wab (bf16, 512KB each), Ab/Mb (bf16, 128KB each),
    //   order (200KB), counters
    // EX (12.8MB) and DEN (12.8MB) live in d_out (51.2MB f32), both dead before k_out.
    const size_t SZH = (size_t)N_NODES * D * 2;          // 25,600,000
    const size_t WSZ = (size_t)N_T * D * D;              // 262144 elements
    const size_t RSZ = (size_t)N_R * N_H * DKD * DKD;    // 65536 elements
    u16* Kb  = (u16*)(ws);
    u16* Qb  = (u16*)(ws + SZH);
    u16* Vb  = (u16*)(ws + 2 * SZH);
    float* ACC = (float*)(ws);                  // aliases Kb+Qb
    u16* TBF  = (u16*)(ws + 2 * SZH);           // aliases Vb
    u16* Wkb = (u16*)(ws + 3 * SZH);
    u16* Wqb = Wkb + WSZ;
    u16* Wvb = Wqb + WSZ;
    u16* Wab = Wvb + WSZ;
    u16* Ab  = Wab + WSZ;
    u16* Mb  = Ab + RSZ;
    int* order = (int*)(Mb + RSZ);
    int* small = order + N_NODES;
    int* cnt  = small;        // 4
    int* cur  = small + 4;    // 4
    int* offp = small + 8;    // 5
    int* toffp= small + 13;   // 5
    float* EX  = (float*)d_out;                               // 12.8 MB
    float* DEN = (float*)((char*)d_out + (size_t)N_EDGES * N_H * 4); // 12.8 MB

    hipMemsetAsync(small, 0, 8 * sizeof(int), stream);
    hipMemsetAsync(DEN, 0, (size_t)N_NODES * N_R * N_H * 4, stream);

    // weight conversions (f32 -> bf16)
    k_cvt4<<<(WSZ / 4 + 255) / 256, 256, 0, stream>>>((const float4*)Wk, (ushort4*)Wkb, WSZ / 4);
    k_cvt4<<<(WSZ / 4 + 255) / 256, 256, 0, stream>>>((const float4*)Wq, (ushort4*)Wqb, WSZ / 4);
    k_cvt4<<<(WSZ / 4 + 255) / 256, 256, 0, stream>>>((const float4*)Wv, (ushort4*)Wvb, WSZ / 4);
    k_cvt4<<<(WSZ / 4 + 255) / 256, 256, 0, stream>>>((const float4*)Wa, (ushort4*)Wab, WSZ / 4);
    k_cvt4<<<(RSZ / 4 + 255) / 256, 256, 0, stream>>>((const float4*)rel_att, (ushort4*)Ab, RSZ / 4);
    k_cvt4<<<(RSZ / 4 + 255) / 256, 256, 0, stream>>>((const float4*)rel_msg, (ushort4*)Mb, RSZ / 4);

    k_hist<<<(N_NODES + 255) / 256, 256, 0, stream>>>(node_type, cnt);
    k_scan<<<1, 1, 0, stream>>>(cnt, offp, toffp);
    k_scatter<<<(N_NODES + 255) / 256, 256, 0, stream>>>(node_type, offp, cur, order);

    k_proj<<<PROJ_BLOCKS, 256, 0, stream>>>(x, order, offp, toffp,
                                            Wkb, bk, Wqb, bq, Wvb, bv, Kb, Qb, Vb);

    k_edge_att<<<(N_EDGES * N_H + 255) / 256, 256, 0, stream>>>(
        Kb, Qb, src, dst, etype, Ab, rel_pri, EX, DEN);

    // ACC aliases Kb/Qb: zero only after the att pass consumed K/Q
    hipMemsetAsync(ACC, 0, 2 * SZH, stream);

    k_edge_msg<<<(N_EDGES * N_H + 255) / 256, 256, 0, stream>>>(
        Vb, src, dst, etype, Mb, EX, DEN, ACC);

    k_node_t<<<N_NODES, 256, 0, stream>>>(ACC, DEN, TBF);

    k_out<<<PROJ_BLOCKS, 256, 0, stream>>>(TBF, x, order, offp, toffp,
                                           Wab, ba, skip, out);
}

// Round 4
// 2656.808 us; speedup vs baseline: 2.6659x; 2.6659x over previous
//
#include <hip/hip_runtime.h>
#include <math.h>
#include <stdint.h>

#define N_NODES 50000
#define N_EDGES 400000
#define N_T 4
#define N_R 8
#define N_H 8
#define DKD 32
#define D 256
#define TM 64
#define PROJ_BLOCKS ((N_NODES + TM - 1) / TM + N_T)   // 786 >= sum of per-type ceils

typedef __bf16 v8bf __attribute__((ext_vector_type(8)));
typedef float v4f __attribute__((ext_vector_type(4)));
typedef unsigned short u16;

__device__ __forceinline__ float bf2f(u16 u) {
    return __uint_as_float(((unsigned int)u) << 16);
}
__device__ __forceinline__ u16 f2bf(float f) {
    unsigned int u = __float_as_uint(f);
    u += 0x7fffu + ((u >> 16) & 1u);          // RNE
    return (u16)(u >> 16);
}

// load 32 contiguous bf16 -> 32 floats (4x 16B loads)
__device__ __forceinline__ void load_bf32(const u16* __restrict__ p, float* f) {
    const uint4* p4 = (const uint4*)p;
    #pragma unroll
    for (int j = 0; j < 4; j++) {
        uint4 u = p4[j];
        f[8 * j + 0] = __uint_as_float(u.x << 16);
        f[8 * j + 1] = __uint_as_float(u.x & 0xffff0000u);
        f[8 * j + 2] = __uint_as_float(u.y << 16);
        f[8 * j + 3] = __uint_as_float(u.y & 0xffff0000u);
        f[8 * j + 4] = __uint_as_float(u.z << 16);
        f[8 * j + 5] = __uint_as_float(u.z & 0xffff0000u);
        f[8 * j + 6] = __uint_as_float(u.w << 16);
        f[8 * j + 7] = __uint_as_float(u.w & 0xffff0000u);
    }
}

// dot of 8 bf16 pairs packed in uint4s
__device__ __forceinline__ float dot8(uint4 m, uint4 v) {
    float s;
    s  = __uint_as_float(m.x << 16)          * __uint_as_float(v.x << 16);
    s += __uint_as_float(m.x & 0xffff0000u)  * __uint_as_float(v.x & 0xffff0000u);
    s += __uint_as_float(m.y << 16)          * __uint_as_float(v.y << 16);
    s += __uint_as_float(m.y & 0xffff0000u)  * __uint_as_float(v.y & 0xffff0000u);
    s += __uint_as_float(m.z << 16)          * __uint_as_float(v.z << 16);
    s += __uint_as_float(m.z & 0xffff0000u)  * __uint_as_float(v.z & 0xffff0000u);
    s += __uint_as_float(m.w << 16)          * __uint_as_float(v.w << 16);
    s += __uint_as_float(m.w & 0xffff0000u)  * __uint_as_float(v.w & 0xffff0000u);
    return s;
}

// ---------------- f32 -> bf16 conversion (weights) ----------------
__global__ __launch_bounds__(256) void k_cvt4(const float4* __restrict__ s,
                                              ushort4* __restrict__ d, int n4) {
    int i = blockIdx.x * 256 + threadIdx.x;
    if (i < n4) {
        float4 v = s[i];
        ushort4 o;
        o.x = f2bf(v.x); o.y = f2bf(v.y); o.z = f2bf(v.z); o.w = f2bf(v.w);
        d[i] = o;
    }
}

// rel_msg [mat][d0][f] f32 -> Mt [mat][f][d0] bf16 (per 32x32 matrix transpose)
__global__ __launch_bounds__(256) void k_cvt_t(const float* __restrict__ s,
                                               u16* __restrict__ d) {
    int i = blockIdx.x * 256 + threadIdx.x;
    if (i >= N_R * N_H * DKD * DKD) return;
    int mat = i >> 10, w = i & 1023;
    int d0 = w >> 5, f = w & 31;
    d[(mat << 10) + f * DKD + d0] = f2bf(s[i]);
}

// ---------------- bucketing by node type ----------------
__global__ void k_hist(const int* __restrict__ nt, int* __restrict__ cnt) {
    int n = blockIdx.x * blockDim.x + threadIdx.x;
    if (n < N_NODES) atomicAdd(&cnt[nt[n]], 1);
}

__global__ void k_scan(const int* __restrict__ cnt, int* __restrict__ off,
                       int* __restrict__ toff) {
    int o = 0, to = 0;
    for (int t = 0; t < N_T; t++) {
        off[t] = o; toff[t] = to;
        o += cnt[t]; to += (cnt[t] + TM - 1) / TM;
    }
    off[N_T] = o; toff[N_T] = to;
}

__global__ void k_scatter(const int* __restrict__ nt, const int* __restrict__ off,
                          int* __restrict__ cur, int* __restrict__ order) {
    int n = blockIdx.x * blockDim.x + threadIdx.x;
    if (n >= N_NODES) return;
    int t = nt[n];
    int pos = off[t] + atomicAdd(&cur[t], 1);
    order[pos] = n;
}

// ---------------- dst-CSR build ----------------
__global__ void k_hist2(const int* __restrict__ dst, int* __restrict__ cnt2) {
    int e = blockIdx.x * blockDim.x + threadIdx.x;
    if (e < N_EDGES) atomicAdd(&cnt2[dst[e]], 1);
}

// single-block exclusive scan of 50000 counters -> rowptr[50001]
__global__ __launch_bounds__(1024) void k_scan2(const int* __restrict__ cnt2,
                                                int* __restrict__ rowptr) {
    __shared__ int sh[1024];
    __shared__ int carry;
    int tid = threadIdx.x;
    if (tid == 0) carry = 0;
    __syncthreads();
    for (int base = 0; base < N_NODES; base += 1024) {
        int i = base + tid;
        int v = (i < N_NODES) ? cnt2[i] : 0;
        sh[tid] = v;
        __syncthreads();
        #pragma unroll
        for (int ofs = 1; ofs < 1024; ofs <<= 1) {
            int t = (tid >= ofs) ? sh[tid - ofs] : 0;
            __syncthreads();
            sh[tid] += t;
            __syncthreads();
        }
        if (i < N_NODES) rowptr[i] = carry + sh[tid] - v;   // exclusive
        int total = sh[1023];
        __syncthreads();
        if (tid == 0) carry += total;
        __syncthreads();
    }
    if (tid == 0) rowptr[N_NODES] = carry;   // == N_EDGES
}

__global__ void k_scatter2(const int* __restrict__ dst, const int* __restrict__ rowptr,
                           int* __restrict__ cur2, int* __restrict__ eidx) {
    int e = blockIdx.x * blockDim.x + threadIdx.x;
    if (e >= N_EDGES) return;
    int d = dst[e];
    int pos = rowptr[d] + atomicAdd(&cur2[d], 1);
    eidx[pos] = e;
}

// ---------------- fused typed K/Q/V projection (MFMA) ----------------
__global__ __launch_bounds__(256) void k_proj(
    const float* __restrict__ x, const int* __restrict__ order,
    const int* __restrict__ off, const int* __restrict__ toff,
    const u16* __restrict__ Wkb, const float* __restrict__ bk,
    const u16* __restrict__ Wqb, const float* __restrict__ bq,
    const u16* __restrict__ Wvb, const float* __restrict__ bv,
    u16* __restrict__ Kb, u16* __restrict__ Qb, u16* __restrict__ Vb) {
    __shared__ __align__(16) u16 xs[TM][D + 8];
    int b = blockIdx.x;
    int t = -1;
    #pragma unroll
    for (int i = 0; i < N_T; i++)
        if (b >= toff[i] && b < toff[i + 1]) t = i;
    if (t < 0) return;
    int nodeBase = off[t] + (b - toff[t]) * TM;
    int count = min(TM, off[t + 1] - nodeBase);
    int tid = threadIdx.x;

    for (int j = tid; j < TM * (D / 4); j += 256) {
        int row = j >> 6, ch = j & 63;
        float4 v = {0.f, 0.f, 0.f, 0.f};
        if (row < count) {
            int g = order[nodeBase + row];
            v = *(const float4*)(x + (size_t)g * D + ch * 4);
        }
        ushort4 o;
        o.x = f2bf(v.x); o.y = f2bf(v.y); o.z = f2bf(v.z); o.w = f2bf(v.w);
        *(ushort4*)&xs[row][ch * 4] = o;
    }
    __syncthreads();

    int lane = tid & 63, wave = tid >> 6;
    int m = lane & 15, quad = lane >> 4;
    v8bf a[8];
    #pragma unroll
    for (int ks = 0; ks < 8; ks++)
        a[ks] = *(const v8bf*)&xs[wave * 16 + m][ks * 32 + quad * 8];

    int grow[4]; bool vrow[4];
    #pragma unroll
    for (int r = 0; r < 4; r++) {
        int rowi = wave * 16 + quad * 4 + r;
        vrow[r] = (rowi < count);
        grow[r] = vrow[r] ? order[nodeBase + rowi] : 0;
    }

    const u16* Ws[3] = {Wkb + (size_t)t * D * D, Wqb + (size_t)t * D * D, Wvb + (size_t)t * D * D};
    const float* Bs[3] = {bk + t * D, bq + t * D, bv + t * D};
    u16* Os[3] = {Kb, Qb, Vb};

    for (int p = 0; p < 3; p++) {
        const u16* W = Ws[p];
        for (int dt = 0; dt < 16; dt++) {
            int dcol = dt * 16 + m;
            v4f acc = {0.f, 0.f, 0.f, 0.f};
            #pragma unroll
            for (int ks = 0; ks < 8; ks++) {
                v8bf bf = *(const v8bf*)(W + (size_t)dcol * D + ks * 32 + quad * 8);
                acc = __builtin_amdgcn_mfma_f32_16x16x32_bf16(a[ks], bf, acc, 0, 0, 0);
            }
            float bias = Bs[p][dcol];
            #pragma unroll
            for (int r = 0; r < 4; r++) {
                if (vrow[r])
                    Os[p][(size_t)grow[r] * D + dcol] = f2bf(acc[r] + bias);
            }
        }
    }
}

// ---------------- edge attention: ex + denom ----------------
__global__ __launch_bounds__(256) void k_edge_att(
    const u16* __restrict__ Kb, const u16* __restrict__ Qb,
    const int* __restrict__ src, const int* __restrict__ dst, const int* __restrict__ et,
    const u16* __restrict__ Ab, const float* __restrict__ pri,
    float* __restrict__ EX, float* __restrict__ DEN) {
    int idx = blockIdx.x * 256 + threadIdx.x;
    if (idx >= N_EDGES * N_H) return;
    int e = idx >> 3, h = idx & 7;
    int s = src[e], d = dst[e], r = et[e];

    float qv[DKD], kv[DKD];
    load_bf32(Qb + (size_t)d * D + h * DKD, qv);
    load_bf32(Kb + (size_t)s * D + h * DKD, kv);

    const u16* A = Ab + ((size_t)(r * N_H + h)) * DKD * DKD;
    float att = 0.f;
    #pragma unroll 4
    for (int d0 = 0; d0 < DKD; d0++) {
        const unsigned int* Ar = (const unsigned int*)(A + (size_t)d0 * DKD);
        float tmp = 0.f;
        #pragma unroll
        for (int j = 0; j < 16; j++) {
            unsigned int u = Ar[j];
            tmp += __uint_as_float(u << 16) * qv[2 * j]
                 + __uint_as_float(u & 0xffff0000u) * qv[2 * j + 1];
        }
        att += kv[d0] * tmp;
    }
    att *= pri[r * N_H + h] * 0.17677669529663687f;   // 1/sqrt(32)
    float ex = __expf(att);
    EX[idx] = ex;
    unsafeAtomicAdd(&DEN[((size_t)d * N_R + r) * N_H + h], ex);
}

// ---------------- gather messages per dst node (no atomics) ----------------
// one wave per node; lane = h*8 + fl, lane handles f in [fl*4, fl*4+4)
__global__ __launch_bounds__(256) void k_gather_msg(
    const u16* __restrict__ Vb, const int* __restrict__ src, const int* __restrict__ et,
    const int* __restrict__ rowptr, const int* __restrict__ eidx,
    const u16* __restrict__ Mtb, const float* __restrict__ EX,
    const float* __restrict__ DEN, u16* __restrict__ TBF) {
    int wave = threadIdx.x >> 6, lane = threadIdx.x & 63;
    int n = blockIdx.x * 4 + wave;
    if (n >= N_NODES) return;
    int h = lane >> 3, fb = (lane & 7) * 4;

    // per-lane denominator reciprocal for (r=lane>>3, h=lane&7)
    int rr = lane >> 3, hh = lane & 7;
    float den = DEN[((size_t)n * N_R + rr) * N_H + hh];
    float invd = (den > 0.f) ? (1.f / den) : 0.f;
    unsigned long long bal = __ballot(den > 0.f);
    int P = __popcll(bal & 0x0101010101010101ULL);   // distinct present etypes
    float invp = (P > 0) ? (1.f / (float)P) : 1.f;

    float acc[4] = {0.f, 0.f, 0.f, 0.f};
    int start = rowptr[n], end = rowptr[n + 1];
    for (int ei = start; ei < end; ei++) {
        int e = eidx[ei];
        int r = et[e], s = src[e];
        float w = EX[(size_t)e * N_H + h] * __shfl(invd, r * 8 + h, 64);
        const uint4* vp = (const uint4*)(Vb + (size_t)s * D + h * DKD);
        uint4 v0 = vp[0], v1 = vp[1], v2 = vp[2], v3 = vp[3];
        const u16* mp = Mtb + (((size_t)r * N_H + h) * DKD + fb) * DKD;
        #pragma unroll
        for (int j = 0; j < 4; j++) {
            const uint4* mr = (const uint4*)(mp + j * DKD);
            float s4 = dot8(mr[0], v0) + dot8(mr[1], v1) + dot8(mr[2], v2) + dot8(mr[3], v3);
            acc[j] += w * s4;
        }
    }
    ushort4 o;
    o.x = f2bf(acc[0] * invp); o.y = f2bf(acc[1] * invp);
    o.z = f2bf(acc[2] * invp); o.w = f2bf(acc[3] * invp);
    *(ushort4*)(TBF + (size_t)n * D + h * DKD + fb) = o;
}

// ---------------- typed output linear + sigmoid-skip blend (MFMA) ----------------
__global__ __launch_bounds__(256) void k_out(
    const u16* __restrict__ TBF, const float* __restrict__ x,
    const int* __restrict__ order, const int* __restrict__ off, const int* __restrict__ toff,
    const u16* __restrict__ Wab, const float* __restrict__ ba,
    const float* __restrict__ skip, float* __restrict__ out) {
    __shared__ __align__(16) u16 xs[TM][D + 8];
    int b = blockIdx.x;
    int t = -1;
    #pragma unroll
    for (int i = 0; i < N_T; i++)
        if (b >= toff[i] && b < toff[i + 1]) t = i;
    if (t < 0) return;
    int nodeBase = off[t] + (b - toff[t]) * TM;
    int count = min(TM, off[t + 1] - nodeBase);
    int tid = threadIdx.x;

    for (int j = tid; j < TM * 32; j += 256) {
        int row = j >> 5, ch = j & 31;
        ushort4 z = {0, 0, 0, 0};
        if (row < count) {
            int g = order[nodeBase + row];
            const ushort4* p = (const ushort4*)(TBF + (size_t)g * D + ch * 8);
            *(ushort4*)&xs[row][ch * 8] = p[0];
            *(ushort4*)&xs[row][ch * 8 + 4] = p[1];
        } else {
            *(ushort4*)&xs[row][ch * 8] = z;
            *(ushort4*)&xs[row][ch * 8 + 4] = z;
        }
    }
    __syncthreads();

    int lane = tid & 63, wave = tid >> 6;
    int m = lane & 15, quad = lane >> 4;
    v8bf a[8];
    #pragma unroll
    for (int ks = 0; ks < 8; ks++)
        a[ks] = *(const v8bf*)&xs[wave * 16 + m][ks * 32 + quad * 8];

    int grow[4]; bool vrow[4];
    #pragma unroll
    for (int r = 0; r < 4; r++) {
        int rowi = wave * 16 + quad * 4 + r;
        vrow[r] = (rowi < count);
        grow[r] = vrow[r] ? order[nodeBase + rowi] : 0;
    }

    float sv = skip[t];
    float alpha = 1.f / (1.f + __expf(-sv));
    float beta = 1.f - alpha;
    const u16* W = Wab + (size_t)t * D * D;

    for (int dt = 0; dt < 16; dt++) {
        int dcol = dt * 16 + m;
        v4f acc = {0.f, 0.f, 0.f, 0.f};
        #pragma unroll
        for (int ks = 0; ks < 8; ks++) {
            v8bf bf = *(const v8bf*)(W + (size_t)dcol * D + ks * 32 + quad * 8);
            acc = __builtin_amdgcn_mfma_f32_16x16x32_bf16(a[ks], bf, acc, 0, 0, 0);
        }
        float bias = ba[t * D + dcol];
        #pragma unroll
        for (int r = 0; r < 4; r++) {
            if (vrow[r]) {
                size_t o = (size_t)grow[r] * D + dcol;
                out[o] = alpha * (acc[r] + bias) + beta * x[o];
            }
        }
    }
}

// ---------------- launch ----------------
extern "C" void kernel_launch(void* const* d_in, const int* in_sizes, int n_in,
                              void* d_out, int out_size, void* d_ws, size_t ws_size,
                              hipStream_t stream) {
    const float* x       = (const float*)d_in[0];
    const int* node_type = (const int*)d_in[1];
    const int* src       = (const int*)d_in[2];
    const int* dst       = (const int*)d_in[3];
    const int* etype     = (const int*)d_in[4];
    const float* Wk = (const float*)d_in[5];
    const float* bk = (const float*)d_in[6];
    const float* Wq = (const float*)d_in[7];
    const float* bq = (const float*)d_in[8];
    const float* Wv = (const float*)d_in[9];
    const float* bv = (const float*)d_in[10];
    const float* Wa = (const float*)d_in[11];
    const float* ba = (const float*)d_in[12];
    const float* rel_pri = (const float*)d_in[13];
    const float* rel_att = (const float*)d_in[14];
    const float* rel_msg = (const float*)d_in[15];
    const float* skip    = (const float*)d_in[16];
    float* out = (float*)d_out;
    char* ws = (char*)d_ws;

    // ws (~79.7 MB): Kb | Qb | Vb (bf16 node tensors), then bf16 weights,
    // order, counters. TBF (bf16) aliases Kb (dead after k_edge_att).
    const size_t SZH = (size_t)N_NODES * D * 2;          // 25.6 MB
    const size_t WSZ = (size_t)N_T * D * D;              // 262144 elems
    const size_t RSZ = (size_t)N_R * N_H * DKD * DKD;    // 65536 elems
    u16* Kb  = (u16*)(ws);
    u16* Qb  = (u16*)(ws + SZH);
    u16* Vb  = (u16*)(ws + 2 * SZH);
    u16* TBF = (u16*)(ws);                      // aliases Kb
    u16* Wkb = (u16*)(ws + 3 * SZH);
    u16* Wqb = Wkb + WSZ;
    u16* Wvb = Wqb + WSZ;
    u16* Wab = Wvb + WSZ;
    u16* Ab  = Wab + WSZ;
    u16* Mtb = Ab + RSZ;
    int* order = (int*)(Mtb + RSZ);
    int* small = order + N_NODES;
    int* cnt  = small;        // 4
    int* cur  = small + 4;    // 4
    int* offp = small + 8;    // 5
    int* toffp= small + 13;   // 5

    // d_out as scratch (all dead before k_out rewrites it):
    //   EX 12.8MB | DEN 12.8MB | rowptr | cnt2 | cur2 | eidx
    char* ob = (char*)d_out;
    float* EX  = (float*)ob;                                   // 3.2M f32
    float* DEN = (float*)(ob + (size_t)N_EDGES * N_H * 4);     // 3.2M f32
    char* ob2 = ob + 2 * (size_t)N_EDGES * N_H * 4;
    int* rowptr = (int*)ob2;                       // 50001
    int* cnt2   = rowptr + N_NODES + 16;           // 50000
    int* cur2   = cnt2 + N_NODES;                  // 50000
    int* eidx   = cur2 + N_NODES;                  // 400000

    hipMemsetAsync(small, 0, 8 * sizeof(int), stream);
    hipMemsetAsync(DEN, 0, (size_t)N_NODES * N_R * N_H * 4, stream);
    hipMemsetAsync(cnt2, 0, 2 * N_NODES * sizeof(int), stream);

    // weight conversions
    k_cvt4<<<(WSZ / 4 + 255) / 256, 256, 0, stream>>>((const float4*)Wk, (ushort4*)Wkb, WSZ / 4);
    k_cvt4<<<(WSZ / 4 + 255) / 256, 256, 0, stream>>>((const float4*)Wq, (ushort4*)Wqb, WSZ / 4);
    k_cvt4<<<(WSZ / 4 + 255) / 256, 256, 0, stream>>>((const float4*)Wv, (ushort4*)Wvb, WSZ / 4);
    k_cvt4<<<(WSZ / 4 + 255) / 256, 256, 0, stream>>>((const float4*)Wa, (ushort4*)Wab, WSZ / 4);
    k_cvt4<<<(RSZ / 4 + 255) / 256, 256, 0, stream>>>((const float4*)rel_att, (ushort4*)Ab, RSZ / 4);
    k_cvt_t<<<(RSZ + 255) / 256, 256, 0, stream>>>(rel_msg, Mtb);

    // node-type buckets
    k_hist<<<(N_NODES + 255) / 256, 256, 0, stream>>>(node_type, cnt);
    k_scan<<<1, 1, 0, stream>>>(cnt, offp, toffp);
    k_scatter<<<(N_NODES + 255) / 256, 256, 0, stream>>>(node_type, offp, cur, order);

    // dst CSR
    k_hist2<<<(N_EDGES + 255) / 256, 256, 0, stream>>>(dst, cnt2);
    k_scan2<<<1, 1024, 0, stream>>>(cnt2, rowptr);
    k_scatter2<<<(N_EDGES + 255) / 256, 256, 0, stream>>>(dst, rowptr, cur2, eidx);

    k_proj<<<PROJ_BLOCKS, 256, 0, stream>>>(x, order, offp, toffp,
                                            Wkb, bk, Wqb, bq, Wvb, bv, Kb, Qb, Vb);

    k_edge_att<<<(N_EDGES * N_H + 255) / 256, 256, 0, stream>>>(
        Kb, Qb, src, dst, etype, Ab, rel_pri, EX, DEN);

    k_gather_msg<<<(N_NODES + 3) / 4, 256, 0, stream>>>(
        Vb, src, etype, rowptr, eidx, Mtb, EX, DEN, TBF);

    k_out<<<PROJ_BLOCKS, 256, 0, stream>>>(TBF, x, order, offp, toffp,
                                           Wab, ba, skip, out);
}